// Round 11
// baseline (513.201 us; speedup 1.0000x reference)
//
// ---------------------------------------------------------------------------
// THEORY (Round 11)
// R10: 8-phase port FAILED per pre-commit (qkv 138, MfmaUtil 30.5) -> revert
// qkv to R6 core (best: qkv 128, total 412).
// flash (~110-125 us by budget; never in top-5) is not MFMA/VALU/HBM-bound;
// remaining suspect = its own staging structure: 2 syncthreads + K,V
// global->reg->LDS round-trip per kv-tile, for operands that are L2-RESIDENT
// (512 KB/bh, shared by 16 q-blocks). learn_hip m168->m169 measured dropping
// LDS-staging of cache-fit attn operands = +26%.
// CHANGES: (1) qkv/gemm_out = R6 verbatim. (2) flash v2: no Ks/Vt LDS, no
// barriers, K/V fragments read directly from global (L2), per-wave loop
// bound; keep Ps (per-wave), defer-max, prescaled q, setprio. (3) fuse
// 4 casts + rope into one 6-slice kernel (9 -> 5 launches).
// PREDICTED: qkv ~126-132 / MfmaUtil ~34 / conflicts 0; flash -> 75-95 us;
// total 412 -> 365-385. FALSIFIER: total >= ~405 -> flash is K/V-load
// latency-bound -> next lever is per-wave reuse (wider Q tile), not schedule.
// ---------------------------------------------------------------------------
#include <hip/hip_runtime.h>
#include <hip/hip_bf16.h>

using bf16 = __hip_bfloat16;
typedef __attribute__((ext_vector_type(8))) short short8;
typedef __attribute__((ext_vector_type(4))) float floatx4;
typedef __attribute__((ext_vector_type(2))) float floatx2;

#define GLDS16(g, l)                                                        \
  __builtin_amdgcn_global_load_lds(                                         \
      (const __attribute__((address_space(1))) void*)(g),                   \
      (__attribute__((address_space(3))) void*)(l), 16, 0, 0)

#define MFMA16(a, b, c) __builtin_amdgcn_mfma_f32_16x16x32_bf16(a, b, c, 0, 0, 0)

__device__ __forceinline__ short f2b(float x) {
  union { bf16 h; short s; } u;
  u.h = __float2bfloat16(x);
  return u.s;
}
__device__ __forceinline__ void st(float* p, float v) { *p = v; }
__device__ __forceinline__ void st(bf16* p, float v) { *p = __float2bfloat16(v); }

// ---- DPP cross-lane (stays off the LDS pipe) ------------------------------
template <int CTRL>
__device__ __forceinline__ float dpp_f(float x) {
  return __int_as_float(__builtin_amdgcn_update_dpp(
      0, __float_as_int(x), CTRL, 0xF, 0xF, true));
}
__device__ __forceinline__ float red16_max(float x) {
  x = fmaxf(x, dpp_f<0xB1>(x));    // quad_perm xor1
  x = fmaxf(x, dpp_f<0x4E>(x));    // quad_perm xor2
  x = fmaxf(x, dpp_f<0x141>(x));   // row_half_mirror
  x = fmaxf(x, dpp_f<0x140>(x));   // row_mirror
  return x;
}
__device__ __forceinline__ float red16_sum(float x) {
  x += dpp_f<0xB1>(x);
  x += dpp_f<0x4E>(x);
  x += dpp_f<0x141>(x);
  x += dpp_f<0x140>(x);
  return x;
}

// ---------------------------------------------------------------------------
// Fused pre-pass: 6 slices of (x lo, x hi, wq, wk, wv) casts + rope table.
// grid (2048, 6) x 256 thr; each cast slice = wsz elems, 8/thread.
// ---------------------------------------------------------------------------
__global__ void fused_pre(const float* __restrict__ x,
                          const float* __restrict__ wq,
                          const float* __restrict__ wk,
                          const float* __restrict__ wv,
                          bf16* __restrict__ xb, bf16* __restrict__ wqb,
                          bf16* __restrict__ wkb, bf16* __restrict__ wvb,
                          floatx2* __restrict__ rtab, long wsz) {
  const int slice = blockIdx.y;
  if (slice == 5) {                      // rope table: 131072 entries
    const int t = blockIdx.x * blockDim.x + threadIdx.x;
    if (t < 131072) {
      const int s = t >> 6, p = t & 63;
      const float invf = exp2f(-(float)p * (13.287712379549449f / 64.0f));
      float sn, cs;
      sincosf((float)s * invf, &sn, &cs);
      floatx2 e; e[0] = cs; e[1] = sn;
      rtab[t] = e;
    }
    return;
  }
  const float* src;
  bf16* dst;
  switch (slice) {
    case 0:  src = x;        dst = xb;        break;
    case 1:  src = x + wsz;  dst = xb + wsz;  break;
    case 2:  src = wq;       dst = wqb;       break;
    case 3:  src = wk;       dst = wkb;       break;
    default: src = wv;       dst = wvb;       break;
  }
  const long i = ((long)blockIdx.x * blockDim.x + threadIdx.x) * 8;
  if (i >= wsz) return;
  floatx4 a = *(const floatx4*)(src + i);
  floatx4 b = *(const floatx4*)(src + i + 4);
  short8 r;
  r[0] = f2b(a[0]); r[1] = f2b(a[1]); r[2] = f2b(a[2]); r[3] = f2b(a[3]);
  r[4] = f2b(b[0]); r[5] = f2b(b[1]); r[6] = f2b(b[2]); r[7] = f2b(b[3]);
  *(short8*)(dst + i) = r;
}

// ---------------------------------------------------------------------------
// fp32 -> bf16 cast (wo only), 8 elems/thread.
// ---------------------------------------------------------------------------
__global__ void cast_kernel(const float* __restrict__ in, bf16* __restrict__ out,
                            long n) {
  long i = ((long)blockIdx.x * blockDim.x + threadIdx.x) * 8;
  if (i >= n) return;
  floatx4 a = *(const floatx4*)(in + i);
  floatx4 b = *(const floatx4*)(in + i + 4);
  short8 r;
  r[0] = f2b(a[0]); r[1] = f2b(a[1]); r[2] = f2b(a[2]); r[3] = f2b(a[3]);
  r[4] = f2b(b[0]); r[5] = f2b(b[1]); r[6] = f2b(b[2]); r[7] = f2b(b[3]);
  *(short8*)(out + i) = r;
}

// ---------------------------------------------------------------------------
// 256x128 / BK=32 core (R6, proven): 256 thr = 4 waves (2Mx2N), wave tile
// 128x64, acc[8][4]. Ring-3 LDS (72 KiB -> 2 blocks/CU). Per K-step:
// vmcnt(6) -> barrier -> 12 ds_read | 6 GLDS (t+2) -> lgkm(0) ->
// sched_barrier -> setprio(1) -> 32 MFMA -> setprio(0).
// Swizzle: 16B-chunk' = chunk ^ ((row>>1)&3) on global SOURCE + ds_read addr;
// LDS dest linear (rule 21). Measured 0 conflicts (R4-R9).
// ---------------------------------------------------------------------------
__device__ __forceinline__ void gemm_core(
    const bf16* __restrict__ A, const bf16* __restrict__ B, int K,
    long m0, long n0, bf16* As, bf16* Bs, floatx4 (&acc)[8][4])
{
  const int tid  = threadIdx.x;
  const int wave = tid >> 6;
  const int lane = tid & 63;
  const int quad = lane >> 4;
  const int l16  = lane & 15;
  const int wr = wave >> 1;     // 0..1 -> rows wr*128
  const int wc = wave & 1;      // 0..1 -> cols wc*64

  long ga[4];
  int aoff[4];
#pragma unroll
  for (int i = 0; i < 4; i++) {
    const int c = i * 256 + tid;
    const int row = c >> 2;
    const int gch = (c & 3) ^ ((c >> 3) & 3);
    ga[i] = (m0 + row) * (long)K + gch * 8;
    aoff[i] = (i * 256 + wave * 64) * 8;     // wave-uniform; +lane*16B in HW
  }
  long gb[2];
  int boff[2];
#pragma unroll
  for (int i = 0; i < 2; i++) {
    const int c = i * 256 + tid;
    const int row = c >> 2;
    const int gch = (c & 3) ^ ((c >> 3) & 3);
    gb[i] = (n0 + row) * (long)K + gch * 8;
    boff[i] = (i * 256 + wave * 64) * 8;
  }

  // read-side swizzled chunk: rows read are 16*x + l16 -> (row>>1)&3 = (l16>>1)&3
  const int qs = (quad ^ ((l16 >> 1) & 3)) * 8;

#pragma unroll
  for (int mi = 0; mi < 8; mi++)
#pragma unroll
    for (int ni = 0; ni < 4; ni++) {
      floatx4 z = {0.f, 0.f, 0.f, 0.f};
      acc[mi][ni] = z;
    }

  const int NT = K >> 5;

  // prologue: stage steps 0,1 into slots 0,1 (6 loads each; 12 in flight)
#pragma unroll
  for (int t = 0; t < 2; t++) {
    bf16* Ad = As + t * 8192;
    bf16* Bd = Bs + t * 4096;
    const long kk = (long)t * 32;
#pragma unroll
    for (int i = 0; i < 4; i++) GLDS16(A + ga[i] + kk, Ad + aoff[i]);
#pragma unroll
    for (int i = 0; i < 2; i++) GLDS16(B + gb[i] + kk, Bd + boff[i]);
  }

  int sl = 0;                    // slot of step t
  for (int t = 0; t < NT; t++) {
    if (t < NT - 1) asm volatile("s_waitcnt vmcnt(6)" ::: "memory");
    else            asm volatile("s_waitcnt vmcnt(0)" ::: "memory");
    __builtin_amdgcn_s_barrier();

    const bf16* Ab = As + sl * 8192;
    const bf16* Bb = Bs + sl * 4096;

    short8 a[8], b[4];
#pragma unroll
    for (int mi = 0; mi < 8; mi++)
      a[mi] = *(const short8*)(Ab + (wr * 128 + mi * 16 + l16) * 32 + qs);
#pragma unroll
    for (int ni = 0; ni < 4; ni++)
      b[ni] = *(const short8*)(Bb + (wc * 64 + ni * 16 + l16) * 32 + qs);

    if (t + 2 < NT) {            // stage step t+2 into slot (t+2)%3
      int s2 = sl + 2; if (s2 >= 3) s2 -= 3;
      bf16* Ad = As + s2 * 8192;
      bf16* Bd = Bs + s2 * 4096;
      const long kk = (long)(t + 2) * 32;
#pragma unroll
      for (int i = 0; i < 4; i++) GLDS16(A + ga[i] + kk, Ad + aoff[i]);
#pragma unroll
      for (int i = 0; i < 2; i++) GLDS16(B + gb[i] + kk, Bd + boff[i]);
    }

    asm volatile("s_waitcnt lgkmcnt(0)" ::: "memory");
    __builtin_amdgcn_sched_barrier(0);
    __builtin_amdgcn_s_setprio(1);
#pragma unroll
    for (int mi = 0; mi < 8; mi++)
#pragma unroll
      for (int ni = 0; ni < 4; ni++)
        acc[mi][ni] = MFMA16(a[mi], b[ni], acc[mi][ni]);
    __builtin_amdgcn_s_setprio(0);

    sl++; if (sl >= 3) sl = 0;
  }
}

// ---------------------------------------------------------------------------
// Fused QKV projection (R6/R9). grid (16, 48): sel = y>>4, n0 = (y&15)*128,
// m0 = x*256. 768 blocks, 2 co-resident/CU. q PRE-SCALED by scale*log2e.
// ---------------------------------------------------------------------------
__global__ __launch_bounds__(256, 2) void qkv_gemm(
    const bf16* __restrict__ A,
    const bf16* __restrict__ B0, const bf16* __restrict__ B1,
    const bf16* __restrict__ B2,
    bf16* __restrict__ C0, bf16* __restrict__ C1, bf16* __restrict__ Cvt,
    const floatx2* __restrict__ rtab,
    int M, int N, int K)
{
  __shared__ __align__(16) bf16 As[3 * 8192];
  __shared__ __align__(16) bf16 Bs[3 * 4096];

  const int sel = blockIdx.y >> 4;
  const long m0 = (long)blockIdx.x * 256;
  const long n0 = (long)(blockIdx.y & 15) * 128;
  const bf16* B = (sel == 0) ? B0 : ((sel == 1) ? B1 : B2);

  floatx4 acc[8][4];
  gemm_core(A, B, K, m0, n0, As, Bs, acc);

  const int tid  = threadIdx.x;
  const int wave = tid >> 6;
  const int lane = tid & 63;
  const int quad = lane >> 4;
  const int l16  = lane & 15;
  const int wr = wave >> 1;
  const int wc = wave & 1;

  if (sel < 2) {
    // RoPE epilogue: pairs (2p,2p+1) in adjacent lanes (l16 bit0).
    bf16* C = (sel == 0) ? C0 : C1;
    const float qscale = (sel == 0)
        ? (0.08838834764831845f * 1.4426950408889634f) : 1.0f;
    const float sgn = (l16 & 1) ? 1.0f : -1.0f;
#pragma unroll
    for (int ni = 0; ni < 4; ni++) {
      const int n = (int)n0 + wc * 64 + ni * 16 + l16;   // h*128 + d
      const int p = (n & 127) >> 1;
#pragma unroll
      for (int mi = 0; mi < 8; mi++) {
        floatx4 v = acc[mi][ni];
        const int mbase = (int)m0 + wr * 128 + mi * 16 + quad * 4;
#pragma unroll
        for (int r = 0; r < 4; r++) {
          const int spos = (mbase + r) & 2047;
          const floatx2 cssn = rtab[spos * 64 + p];
          const float pv = dpp_f<0xB1>(v[r]);       // pair partner
          const float outv = (v[r] * cssn[0] + pv * (sgn * cssn[1])) * qscale;
          st(&C[(long)(mbase + r) * N + n], outv);
        }
      }
    }
  } else {
    // transposed V epilogue: v_t[((b*16+h)*128+d)*2048 + s], 4 s packed
#pragma unroll
    for (int ni = 0; ni < 4; ni++) {
      const int n = (int)n0 + wc * 64 + ni * 16 + l16;   // h*128 + d
      const int hh = n >> 7, d = n & 127;
#pragma unroll
      for (int mi = 0; mi < 8; mi++) {
        floatx4 v = acc[mi][ni];
        const int m = (int)m0 + wr * 128 + mi * 16 + quad * 4;
        const int bb = m >> 11, s = m & 2047;
        unsigned long long pk =
            (unsigned long long)(unsigned short)f2b(v[0]) |
            ((unsigned long long)(unsigned short)f2b(v[1]) << 16) |
            ((unsigned long long)(unsigned short)f2b(v[2]) << 32) |
            ((unsigned long long)(unsigned short)f2b(v[3]) << 48);
        *(unsigned long long*)(Cvt + ((long)((bb * 16 + hh) * 128 + d)) * 2048 + s) = pk;
      }
    }
  }
}

// ---------------------------------------------------------------------------
// Final projection GEMM (bf16 x bf16 -> fp32 out), R6 core.
// grid (16,16) = 256 blocks = exactly 1 full round.
// ---------------------------------------------------------------------------
__global__ __launch_bounds__(256, 2) void gemm_out(
    const bf16* __restrict__ A, const bf16* __restrict__ B,
    float* __restrict__ C, int M, int N, int K)
{
  __shared__ __align__(16) bf16 As[3 * 8192];
  __shared__ __align__(16) bf16 Bs[3 * 4096];
  const long m0 = (long)blockIdx.x * 256;
  const long n0 = (long)blockIdx.y * 128;

  floatx4 acc[8][4];
  gemm_core(A, B, K, m0, n0, As, Bs, acc);

  const int tid  = threadIdx.x;
  const int wave = tid >> 6;
  const int lane = tid & 63;
  const int quad = lane >> 4;
  const int l16  = lane & 15;
  const int wr = wave >> 1;
  const int wc = wave & 1;

#pragma unroll
  for (int mi = 0; mi < 8; mi++)
#pragma unroll
    for (int ni = 0; ni < 4; ni++) {
      floatx4 v = acc[mi][ni];
      const long row = m0 + wr * 128 + mi * 16 + quad * 4;
      const long col = n0 + wc * 64 + ni * 16 + l16;
#pragma unroll
      for (int r = 0; r < 4; r++)
        C[(row + r) * (long)N + col] = v[r];
    }
}

// ---------------------------------------------------------------------------
// Causal flash attention v2 -- ZERO-BARRIER. K and V are L2-resident
// (512 KB per bh, shared by 16 q-blocks), so LDS staging is pure overhead
// (learn_hip m169): K/V fragments are read directly from global inside the
// MFMA loops; no Ks/Vt tiles, no __syncthreads, per-wave loop bound (waves
// fully independent). Ps stays (per-wave LDS scratch, no barrier needed).
// Defer-max (T13), pre-scaled q (scale*log2e folded at qkv), setprio (T5).
// ---------------------------------------------------------------------------
#define NEG_BIG (-30000.0f)

__global__ __launch_bounds__(256) void flash_attn(
    const bf16* __restrict__ q, const bf16* __restrict__ k,
    const bf16* __restrict__ vt, bf16* __restrict__ o, int S)
{
  __shared__ bf16 Ps[4][32 * 72];    // per-wave P scratch, stride 72

  const int tid  = threadIdx.x;
  const int wave = tid >> 6;
  const int lane = tid & 63;
  const int quad = lane >> 4;
  const int l16  = lane & 15;

  const int bh = blockIdx.x;
  const int b  = bh >> 4, h = bh & 15;
  const int q0 = ((int)gridDim.y - 1 - (int)blockIdx.y) * 128;  // heavy first

  const bf16* Qb = q + ((long)b * S * 16 + h) * 128;
  const bf16* Kb = k + ((long)b * S * 16 + h) * 128;
  const bf16* Vg = vt + (long)bh * 128 * S;       // [d][s]
  bf16*       Ob = o + ((long)b * S * 16 + h) * 128;

  short8 aq[2][4];
#pragma unroll
  for (int mi = 0; mi < 2; mi++)
#pragma unroll
    for (int kt = 0; kt < 4; kt++)
      aq[mi][kt] = *(const short8*)(
          Qb + (long)(q0 + wave * 32 + mi * 16 + l16) * 2048 + kt * 32 + quad * 8);

  float m_i[2][4], l_i[2][4];
  floatx4 oacc[2][8];
  const floatx4 zero4 = {0.f, 0.f, 0.f, 0.f};
#pragma unroll
  for (int mi = 0; mi < 2; mi++) {
#pragma unroll
    for (int r = 0; r < 4; r++) { m_i[mi][r] = NEG_BIG; l_i[mi][r] = 0.f; }
#pragma unroll
    for (int dt = 0; dt < 8; dt++) oacc[mi][dt] = zero4;
  }

  const int wrow0 = q0 + wave * 32;
  const int wlast = wrow0 + 31;      // per-wave causal bound

  for (int kt0 = 0; kt0 <= wlast; kt0 += 64) {
    floatx4 sc[2][4];
#pragma unroll
    for (int mi = 0; mi < 2; mi++)
#pragma unroll
      for (int nt = 0; nt < 4; nt++) sc[mi][nt] = zero4;

    // ---- QK^T: K fragments straight from global (L2-hit) ----
    __builtin_amdgcn_s_setprio(1);
#pragma unroll
    for (int nt = 0; nt < 4; nt++)
#pragma unroll
      for (int kt = 0; kt < 4; kt++) {
        short8 bk = *(const short8*)(
            Kb + (long)(kt0 + nt * 16 + l16) * 2048 + kt * 32 + quad * 8);
        sc[0][nt] = __builtin_amdgcn_mfma_f32_16x16x32_bf16(aq[0][kt], bk, sc[0][nt], 0, 0, 0);
        sc[1][nt] = __builtin_amdgcn_mfma_f32_16x16x32_bf16(aq[1][kt], bk, sc[1][nt], 0, 0, 0);
      }
    __builtin_amdgcn_s_setprio(0);

    // ---- pass 1: mask + row max (scores pre-scaled, log2 domain) ----
    const bool needmask = (kt0 + 63 > wrow0);
    float mx[2][4];
    int allskip = 1;
#pragma unroll
    for (int mi = 0; mi < 2; mi++) {
#pragma unroll
      for (int r = 0; r < 4; r++) {
        const int qr = wrow0 + mi * 16 + quad * 4 + r;
        float m = NEG_BIG;
        if (needmask) {
#pragma unroll
          for (int nt = 0; nt < 4; nt++) {
            const int kc2 = kt0 + nt * 16 + l16;
            float vsc = (kc2 <= qr) ? sc[mi][nt][r] : NEG_BIG;
            sc[mi][nt][r] = vsc;
            m = fmaxf(m, vsc);
          }
        } else {
#pragma unroll
          for (int nt = 0; nt < 4; nt++) m = fmaxf(m, sc[mi][nt][r]);
        }
        m = red16_max(m);
        mx[mi][r] = m;
        allskip &= (m <= m_i[mi][r] + 8.0f) ? 1 : 0;
      }
    }

    // ---- defer-max: rescale only when some row max grew past THR=8 ----
    if (!__all(allskip)) {
#pragma unroll
      for (int mi = 0; mi < 2; mi++) {
#pragma unroll
        for (int r = 0; r < 4; r++) {
          const float mnew = fmaxf(m_i[mi][r], mx[mi][r]);
          const float alpha = exp2f(m_i[mi][r] - mnew);
          m_i[mi][r] = mnew;
          l_i[mi][r] *= alpha;
#pragma unroll
          for (int dt = 0; dt < 8; dt++) oacc[mi][dt][r] *= alpha;
        }
      }
    }

    // ---- pass 2: exp + row sum against (possibly stale) m_i ----
#pragma unroll
    for (int mi = 0; mi < 2; mi++) {
#pragma unroll
      for (int r = 0; r < 4; r++) {
        float rs = 0.f;
#pragma unroll
        for (int nt = 0; nt < 4; nt++) {
          float p = exp2f(sc[mi][nt][r] - m_i[mi][r]);
          sc[mi][nt][r] = p;
          rs += p;
        }
        rs = red16_sum(rs);
        l_i[mi][r] += rs;
      }
    }

    // ---- P -> LDS (per-wave, no barrier) ----
#pragma unroll
    for (int mi = 0; mi < 2; mi++)
#pragma unroll
      for (int nt = 0; nt < 4; nt++)
#pragma unroll
        for (int r = 0; r < 4; r++)
          Ps[wave][(mi * 16 + quad * 4 + r) * 72 + nt * 16 + l16] =
              __float2bfloat16(sc[mi][nt][r]);

    // ---- PV: V^T fragments straight from global (L2-hit) ----
    __builtin_amdgcn_s_setprio(1);
#pragma unroll
    for (int ks = 0; ks < 2; ks++) {
      short8 ap0 = *(const short8*)(&Ps[wave][(l16) * 72 + ks * 32 + quad * 8]);
      short8 ap1 = *(const short8*)(&Ps[wave][(16 + l16) * 72 + ks * 32 + quad * 8]);
#pragma unroll
      for (int dt = 0; dt < 8; dt++) {
        short8 bv = *(const short8*)(
            Vg + (long)(dt * 16 + l16) * S + kt0 + ks * 32 + quad * 8);
        oacc[0][dt] = __builtin_amdgcn_mfma_f32_16x16x32_bf16(ap0, bv, oacc[0][dt], 0, 0, 0);
        oacc[1][dt] = __builtin_amdgcn_mfma_f32_16x16x32_bf16(ap1, bv, oacc[1][dt], 0, 0, 0);
      }
    }
    __builtin_amdgcn_s_setprio(0);
  }

#pragma unroll
  for (int mi = 0; mi < 2; mi++)
#pragma unroll
    for (int r = 0; r < 4; r++) {
      const float inv = 1.0f / l_i[mi][r];
      const long s = q0 + wave * 32 + mi * 16 + quad * 4 + r;
#pragma unroll
      for (int dt = 0; dt < 8; dt++)
        Ob[s * 2048 + dt * 16 + l16] = __float2bfloat16(oacc[mi][dt][r] * inv);
    }
}

// ---------------------------------------------------------------------------
extern "C" void kernel_launch(void* const* d_in, const int* in_sizes, int n_in,
                              void* d_out, int out_size, void* d_ws, size_t ws_size,
                              hipStream_t stream) {
  const float* x  = (const float*)d_in[0];
  const float* wq = (const float*)d_in[1];
  const float* wk = (const float*)d_in[2];
  const float* wv = (const float*)d_in[3];
  const float* wo = (const float*)d_in[4];
  float* out = (float*)d_out;

  const int B = 2, S = 2048, D = 2048, H = 16;
  const int M = B * S;                    // 4096
  const long tsz = (long)M * D;           // 8.39M elems
  const long wsz = (long)D * D;           // 4.19M elems

  if (ws_size < 4 * (size_t)tsz * sizeof(bf16)) return;   // 67 MB

  bf16* qb  = (bf16*)d_ws;
  bf16* kb  = qb + tsz;
  bf16* vtb = kb + tsz;                   // transposed V: [b][h][d][s]
  bf16* ab  = vtb + tsz;

  // d_out as scratch: xb (tsz) + wq' (wsz) + wk' (wsz) = exactly out bytes.
  bf16* xb  = (bf16*)d_out;
  bf16* wqb = xb + tsz;
  bf16* wkb = wqb + wsz;
  bf16* wvb = ab;                         // front half of ab (dead until flash)
  floatx2* rtab = (floatx2*)(ab + wsz);   // 1 MB rope table in ab's back half
  bf16* wob = qb;                         // qb dead after flash

  fused_pre<<<dim3((int)(wsz / 8 / 256), 6), 256, 0, stream>>>(
      x, wq, wk, wv, xb, wqb, wkb, wvb, rtab, wsz);

  qkv_gemm<<<dim3(16, 48), 256, 0, stream>>>(
      xb, wqb, wkb, wvb, qb, kb, vtb, rtab, M, D, D);

  flash_attn<<<dim3(B * H, S / 128), 256, 0, stream>>>(qb, kb, vtb, ab, S);

  cast_kernel<<<(int)(wsz / 8 / 256), 256, 0, stream>>>(wo, wob, wsz);
  gemm_out<<<dim3(16, 16), 256, 0, stream>>>(ab, wob, out, M, D, D);
}

// Round 12
// 410.830 us; speedup vs baseline: 1.2492x; 1.2492x over previous
//
// ---------------------------------------------------------------------------
// THEORY (Round 12)
// R11: flash v2 (no-LDS) FALSIFIED hard: 230 us, MfmaUtil 6% -- per-fragment
// global K/V reads are 64-lane scatters (4KB row stride); LDS staging is what
// coalesces them. Revert flash to v1 (R9).
// R11's bracketing exposed the real target: gemm_out ~115 us (~300 TF) --
// its 256-block grid = 1 block/CU, but the R6 core's 35% MfmaUtil REQUIRES
// 2-block co-residency (R5->R6 isolated: 1/CU=31% lockstep, 2/CU=35% +
// partner hides barrier drains).
// CHANGE: gemm_out -> 128x128 tile, 4 waves (2Mx2N, wave 64x64, acc[4][4]),
// BK=32, ring-3 LDS 48 KiB, grid (32,16)=512 blocks = 2 co-resident/CU.
// Same swizzle / counted vmcnt(4) / pinned schedule. qkv+flash+pre unchanged.
// PREDICTED: gemm_out 115 -> 55-65 us (LDS 49152, MfmaUtil 31-36, confl 0);
// qkv ~126-132 / flash ~115-125 (revert checks; flash may enter top-5);
// total -> ~355-370. FALSIFIER: gemm_out >= ~90 -> co-residency theory wrong.
// ---------------------------------------------------------------------------
#include <hip/hip_runtime.h>
#include <hip/hip_bf16.h>

using bf16 = __hip_bfloat16;
typedef __attribute__((ext_vector_type(8))) short short8;
typedef __attribute__((ext_vector_type(4))) float floatx4;
typedef __attribute__((ext_vector_type(2))) float floatx2;

#define GLDS16(g, l)                                                        \
  __builtin_amdgcn_global_load_lds(                                         \
      (const __attribute__((address_space(1))) void*)(g),                   \
      (__attribute__((address_space(3))) void*)(l), 16, 0, 0)

#define MFMA16(a, b, c) __builtin_amdgcn_mfma_f32_16x16x32_bf16(a, b, c, 0, 0, 0)

__device__ __forceinline__ short f2b(float x) {
  union { bf16 h; short s; } u;
  u.h = __float2bfloat16(x);
  return u.s;
}
__device__ __forceinline__ void st(float* p, float v) { *p = v; }
__device__ __forceinline__ void st(bf16* p, float v) { *p = __float2bfloat16(v); }

// ---- DPP cross-lane (stays off the LDS pipe) ------------------------------
template <int CTRL>
__device__ __forceinline__ float dpp_f(float x) {
  return __int_as_float(__builtin_amdgcn_update_dpp(
      0, __float_as_int(x), CTRL, 0xF, 0xF, true));
}
__device__ __forceinline__ float red16_max(float x) {
  x = fmaxf(x, dpp_f<0xB1>(x));    // quad_perm xor1
  x = fmaxf(x, dpp_f<0x4E>(x));    // quad_perm xor2
  x = fmaxf(x, dpp_f<0x141>(x));   // row_half_mirror
  x = fmaxf(x, dpp_f<0x140>(x));   // row_mirror
  return x;
}
__device__ __forceinline__ float red16_sum(float x) {
  x += dpp_f<0xB1>(x);
  x += dpp_f<0x4E>(x);
  x += dpp_f<0x141>(x);
  x += dpp_f<0x140>(x);
  return x;
}

// ---------------------------------------------------------------------------
// Fused pre-pass: 6 slices of (x lo, x hi, wq, wk, wv) casts + rope table.
// ---------------------------------------------------------------------------
__global__ void fused_pre(const float* __restrict__ x,
                          const float* __restrict__ wq,
                          const float* __restrict__ wk,
                          const float* __restrict__ wv,
                          bf16* __restrict__ xb, bf16* __restrict__ wqb,
                          bf16* __restrict__ wkb, bf16* __restrict__ wvb,
                          floatx2* __restrict__ rtab, long wsz) {
  const int slice = blockIdx.y;
  if (slice == 5) {                      // rope table: 131072 entries
    const int t = blockIdx.x * blockDim.x + threadIdx.x;
    if (t < 131072) {
      const int s = t >> 6, p = t & 63;
      const float invf = exp2f(-(float)p * (13.287712379549449f / 64.0f));
      float sn, cs;
      sincosf((float)s * invf, &sn, &cs);
      floatx2 e; e[0] = cs; e[1] = sn;
      rtab[t] = e;
    }
    return;
  }
  const float* src;
  bf16* dst;
  switch (slice) {
    case 0:  src = x;        dst = xb;        break;
    case 1:  src = x + wsz;  dst = xb + wsz;  break;
    case 2:  src = wq;       dst = wqb;       break;
    case 3:  src = wk;       dst = wkb;       break;
    default: src = wv;       dst = wvb;       break;
  }
  const long i = ((long)blockIdx.x * blockDim.x + threadIdx.x) * 8;
  if (i >= wsz) return;
  floatx4 a = *(const floatx4*)(src + i);
  floatx4 b = *(const floatx4*)(src + i + 4);
  short8 r;
  r[0] = f2b(a[0]); r[1] = f2b(a[1]); r[2] = f2b(a[2]); r[3] = f2b(a[3]);
  r[4] = f2b(b[0]); r[5] = f2b(b[1]); r[6] = f2b(b[2]); r[7] = f2b(b[3]);
  *(short8*)(dst + i) = r;
}

// ---------------------------------------------------------------------------
// fp32 -> bf16 cast (wo only), 8 elems/thread.
// ---------------------------------------------------------------------------
__global__ void cast_kernel(const float* __restrict__ in, bf16* __restrict__ out,
                            long n) {
  long i = ((long)blockIdx.x * blockDim.x + threadIdx.x) * 8;
  if (i >= n) return;
  floatx4 a = *(const floatx4*)(in + i);
  floatx4 b = *(const floatx4*)(in + i + 4);
  short8 r;
  r[0] = f2b(a[0]); r[1] = f2b(a[1]); r[2] = f2b(a[2]); r[3] = f2b(a[3]);
  r[4] = f2b(b[0]); r[5] = f2b(b[1]); r[6] = f2b(b[2]); r[7] = f2b(b[3]);
  *(short8*)(out + i) = r;
}

// ---------------------------------------------------------------------------
// 256x128 / BK=32 core (R6, proven) -- qkv. 256 thr = 4 waves (2Mx2N),
// wave tile 128x64, acc[8][4]. Ring-3 (72 KiB -> 2 blocks/CU).
// ---------------------------------------------------------------------------
__device__ __forceinline__ void gemm_core(
    const bf16* __restrict__ A, const bf16* __restrict__ B, int K,
    long m0, long n0, bf16* As, bf16* Bs, floatx4 (&acc)[8][4])
{
  const int tid  = threadIdx.x;
  const int wave = tid >> 6;
  const int lane = tid & 63;
  const int quad = lane >> 4;
  const int l16  = lane & 15;
  const int wr = wave >> 1;     // 0..1 -> rows wr*128
  const int wc = wave & 1;      // 0..1 -> cols wc*64

  long ga[4];
  int aoff[4];
#pragma unroll
  for (int i = 0; i < 4; i++) {
    const int c = i * 256 + tid;
    const int row = c >> 2;
    const int gch = (c & 3) ^ ((c >> 3) & 3);
    ga[i] = (m0 + row) * (long)K + gch * 8;
    aoff[i] = (i * 256 + wave * 64) * 8;     // wave-uniform; +lane*16B in HW
  }
  long gb[2];
  int boff[2];
#pragma unroll
  for (int i = 0; i < 2; i++) {
    const int c = i * 256 + tid;
    const int row = c >> 2;
    const int gch = (c & 3) ^ ((c >> 3) & 3);
    gb[i] = (n0 + row) * (long)K + gch * 8;
    boff[i] = (i * 256 + wave * 64) * 8;
  }

  const int qs = (quad ^ ((l16 >> 1) & 3)) * 8;

#pragma unroll
  for (int mi = 0; mi < 8; mi++)
#pragma unroll
    for (int ni = 0; ni < 4; ni++) {
      floatx4 z = {0.f, 0.f, 0.f, 0.f};
      acc[mi][ni] = z;
    }

  const int NT = K >> 5;

#pragma unroll
  for (int t = 0; t < 2; t++) {
    bf16* Ad = As + t * 8192;
    bf16* Bd = Bs + t * 4096;
    const long kk = (long)t * 32;
#pragma unroll
    for (int i = 0; i < 4; i++) GLDS16(A + ga[i] + kk, Ad + aoff[i]);
#pragma unroll
    for (int i = 0; i < 2; i++) GLDS16(B + gb[i] + kk, Bd + boff[i]);
  }

  int sl = 0;
  for (int t = 0; t < NT; t++) {
    if (t < NT - 1) asm volatile("s_waitcnt vmcnt(6)" ::: "memory");
    else            asm volatile("s_waitcnt vmcnt(0)" ::: "memory");
    __builtin_amdgcn_s_barrier();

    const bf16* Ab = As + sl * 8192;
    const bf16* Bb = Bs + sl * 4096;

    short8 a[8], b[4];
#pragma unroll
    for (int mi = 0; mi < 8; mi++)
      a[mi] = *(const short8*)(Ab + (wr * 128 + mi * 16 + l16) * 32 + qs);
#pragma unroll
    for (int ni = 0; ni < 4; ni++)
      b[ni] = *(const short8*)(Bb + (wc * 64 + ni * 16 + l16) * 32 + qs);

    if (t + 2 < NT) {
      int s2 = sl + 2; if (s2 >= 3) s2 -= 3;
      bf16* Ad = As + s2 * 8192;
      bf16* Bd = Bs + s2 * 4096;
      const long kk = (long)(t + 2) * 32;
#pragma unroll
      for (int i = 0; i < 4; i++) GLDS16(A + ga[i] + kk, Ad + aoff[i]);
#pragma unroll
      for (int i = 0; i < 2; i++) GLDS16(B + gb[i] + kk, Bd + boff[i]);
    }

    asm volatile("s_waitcnt lgkmcnt(0)" ::: "memory");
    __builtin_amdgcn_sched_barrier(0);
    __builtin_amdgcn_s_setprio(1);
#pragma unroll
    for (int mi = 0; mi < 8; mi++)
#pragma unroll
      for (int ni = 0; ni < 4; ni++)
        acc[mi][ni] = MFMA16(a[mi], b[ni], acc[mi][ni]);
    __builtin_amdgcn_s_setprio(0);

    sl++; if (sl >= 3) sl = 0;
  }
}

// ---------------------------------------------------------------------------
// 128x128 / BK=32 core -- gemm_out. 256 thr = 4 waves (2Mx2N), wave tile
// 64x64, acc[4][4]. Ring-3 LDS 48 KiB -> 2 blocks/CU at 512-block grid.
// Per K-step: vmcnt(4) -> barrier -> 8 ds_read | 4 GLDS (t+2) -> lgkm(0) ->
// sched_barrier -> setprio(1) -> 16 MFMA. Same swizzle algebra (0 conflicts).
// ---------------------------------------------------------------------------
__device__ __forceinline__ void gemm_core128(
    const bf16* __restrict__ A, const bf16* __restrict__ B, int K,
    long m0, long n0, bf16* As, bf16* Bs, floatx4 (&acc)[4][4])
{
  const int tid  = threadIdx.x;
  const int wave = tid >> 6;
  const int lane = tid & 63;
  const int quad = lane >> 4;
  const int l16  = lane & 15;
  const int wr = wave >> 1;     // 0..1 -> rows wr*64
  const int wc = wave & 1;      // 0..1 -> cols wc*64

  // A/B staging: 128 rows x 4 chunks = 512 chunks each; 2 chunks/thread.
  long ga[2], gb[2];
  int soff[2];
#pragma unroll
  for (int i = 0; i < 2; i++) {
    const int c = i * 256 + tid;
    const int row = c >> 2;
    const int gch = (c & 3) ^ ((c >> 3) & 3);
    ga[i] = (m0 + row) * (long)K + gch * 8;
    gb[i] = (n0 + row) * (long)K + gch * 8;
    soff[i] = (i * 256 + wave * 64) * 8;     // wave-uniform; +lane*16B in HW
  }

  const int qs = (quad ^ ((l16 >> 1) & 3)) * 8;

#pragma unroll
  for (int mi = 0; mi < 4; mi++)
#pragma unroll
    for (int ni = 0; ni < 4; ni++) {
      floatx4 z = {0.f, 0.f, 0.f, 0.f};
      acc[mi][ni] = z;
    }

  const int NT = K >> 5;

  // prologue: stage steps 0,1 into slots 0,1 (4 loads each; 8 in flight)
#pragma unroll
  for (int t = 0; t < 2; t++) {
    bf16* Ad = As + t * 4096;
    bf16* Bd = Bs + t * 4096;
    const long kk = (long)t * 32;
#pragma unroll
    for (int i = 0; i < 2; i++) GLDS16(A + ga[i] + kk, Ad + soff[i]);
#pragma unroll
    for (int i = 0; i < 2; i++) GLDS16(B + gb[i] + kk, Bd + soff[i]);
  }

  int sl = 0;
  for (int t = 0; t < NT; t++) {
    if (t < NT - 1) asm volatile("s_waitcnt vmcnt(4)" ::: "memory");
    else            asm volatile("s_waitcnt vmcnt(0)" ::: "memory");
    __builtin_amdgcn_s_barrier();

    const bf16* Ab = As + sl * 4096;
    const bf16* Bb = Bs + sl * 4096;

    short8 a[4], b[4];
#pragma unroll
    for (int mi = 0; mi < 4; mi++)
      a[mi] = *(const short8*)(Ab + (wr * 64 + mi * 16 + l16) * 32 + qs);
#pragma unroll
    for (int ni = 0; ni < 4; ni++)
      b[ni] = *(const short8*)(Bb + (wc * 64 + ni * 16 + l16) * 32 + qs);

    if (t + 2 < NT) {
      int s2 = sl + 2; if (s2 >= 3) s2 -= 3;
      bf16* Ad = As + s2 * 4096;
      bf16* Bd = Bs + s2 * 4096;
      const long kk = (long)(t + 2) * 32;
#pragma unroll
      for (int i = 0; i < 2; i++) GLDS16(A + ga[i] + kk, Ad + soff[i]);
#pragma unroll
      for (int i = 0; i < 2; i++) GLDS16(B + gb[i] + kk, Bd + soff[i]);
    }

    asm volatile("s_waitcnt lgkmcnt(0)" ::: "memory");
    __builtin_amdgcn_sched_barrier(0);
    __builtin_amdgcn_s_setprio(1);
#pragma unroll
    for (int mi = 0; mi < 4; mi++)
#pragma unroll
      for (int ni = 0; ni < 4; ni++)
        acc[mi][ni] = MFMA16(a[mi], b[ni], acc[mi][ni]);
    __builtin_amdgcn_s_setprio(0);

    sl++; if (sl >= 3) sl = 0;
  }
}

// ---------------------------------------------------------------------------
// Fused QKV projection (R6/R9). grid (16, 48): sel = y>>4, n0 = (y&15)*128,
// m0 = x*256. 768 blocks, 2 co-resident/CU. q PRE-SCALED by scale*log2e.
// ---------------------------------------------------------------------------
__global__ __launch_bounds__(256, 2) void qkv_gemm(
    const bf16* __restrict__ A,
    const bf16* __restrict__ B0, const bf16* __restrict__ B1,
    const bf16* __restrict__ B2,
    bf16* __restrict__ C0, bf16* __restrict__ C1, bf16* __restrict__ Cvt,
    const floatx2* __restrict__ rtab,
    int M, int N, int K)
{
  __shared__ __align__(16) bf16 As[3 * 8192];
  __shared__ __align__(16) bf16 Bs[3 * 4096];

  const int sel = blockIdx.y >> 4;
  const long m0 = (long)blockIdx.x * 256;
  const long n0 = (long)(blockIdx.y & 15) * 128;
  const bf16* B = (sel == 0) ? B0 : ((sel == 1) ? B1 : B2);

  floatx4 acc[8][4];
  gemm_core(A, B, K, m0, n0, As, Bs, acc);

  const int tid  = threadIdx.x;
  const int wave = tid >> 6;
  const int lane = tid & 63;
  const int quad = lane >> 4;
  const int l16  = lane & 15;
  const int wr = wave >> 1;
  const int wc = wave & 1;

  if (sel < 2) {
    // RoPE epilogue: pairs (2p,2p+1) in adjacent lanes (l16 bit0).
    bf16* C = (sel == 0) ? C0 : C1;
    const float qscale = (sel == 0)
        ? (0.08838834764831845f * 1.4426950408889634f) : 1.0f;
    const float sgn = (l16 & 1) ? 1.0f : -1.0f;
#pragma unroll
    for (int ni = 0; ni < 4; ni++) {
      const int n = (int)n0 + wc * 64 + ni * 16 + l16;   // h*128 + d
      const int p = (n & 127) >> 1;
#pragma unroll
      for (int mi = 0; mi < 8; mi++) {
        floatx4 v = acc[mi][ni];
        const int mbase = (int)m0 + wr * 128 + mi * 16 + quad * 4;
#pragma unroll
        for (int r = 0; r < 4; r++) {
          const int spos = (mbase + r) & 2047;
          const floatx2 cssn = rtab[spos * 64 + p];
          const float pv = dpp_f<0xB1>(v[r]);       // pair partner
          const float outv = (v[r] * cssn[0] + pv * (sgn * cssn[1])) * qscale;
          st(&C[(long)(mbase + r) * N + n], outv);
        }
      }
    }
  } else {
    // transposed V epilogue: v_t[((b*16+h)*128+d)*2048 + s], 4 s packed
#pragma unroll
    for (int ni = 0; ni < 4; ni++) {
      const int n = (int)n0 + wc * 64 + ni * 16 + l16;   // h*128 + d
      const int hh = n >> 7, d = n & 127;
#pragma unroll
      for (int mi = 0; mi < 8; mi++) {
        floatx4 v = acc[mi][ni];
        const int m = (int)m0 + wr * 128 + mi * 16 + quad * 4;
        const int bb = m >> 11, s = m & 2047;
        unsigned long long pk =
            (unsigned long long)(unsigned short)f2b(v[0]) |
            ((unsigned long long)(unsigned short)f2b(v[1]) << 16) |
            ((unsigned long long)(unsigned short)f2b(v[2]) << 32) |
            ((unsigned long long)(unsigned short)f2b(v[3]) << 48);
        *(unsigned long long*)(Cvt + ((long)((bb * 16 + hh) * 128 + d)) * 2048 + s) = pk;
      }
    }
  }
}

// ---------------------------------------------------------------------------
// Final projection GEMM (bf16 x bf16 -> fp32 out), 128x128 core.
// grid (32,16) = 512 blocks = 2 co-resident/CU.
// ---------------------------------------------------------------------------
__global__ __launch_bounds__(256, 2) void gemm_out(
    const bf16* __restrict__ A, const bf16* __restrict__ B,
    float* __restrict__ C, int M, int N, int K)
{
  __shared__ __align__(16) bf16 As[3 * 4096];
  __shared__ __align__(16) bf16 Bs[3 * 4096];
  const long m0 = (long)blockIdx.x * 128;
  const long n0 = (long)blockIdx.y * 128;

  floatx4 acc[4][4];
  gemm_core128(A, B, K, m0, n0, As, Bs, acc);

  const int tid  = threadIdx.x;
  const int wave = tid >> 6;
  const int lane = tid & 63;
  const int quad = lane >> 4;
  const int l16  = lane & 15;
  const int wr = wave >> 1;
  const int wc = wave & 1;

#pragma unroll
  for (int mi = 0; mi < 4; mi++)
#pragma unroll
    for (int ni = 0; ni < 4; ni++) {
      floatx4 v = acc[mi][ni];
      const long row = m0 + wr * 64 + mi * 16 + quad * 4;
      const long col = n0 + wc * 64 + ni * 16 + l16;
#pragma unroll
      for (int r = 0; r < 4; r++)
        C[(row + r) * (long)N + col] = v[r];
    }
}

// ---------------------------------------------------------------------------
// Causal flash attention v1 (R9). LDS-staged K/V (coalesced), reg prefetch,
// defer-max (T13), pre-scaled q, setprio (T5).
// ---------------------------------------------------------------------------
#define NEG_BIG (-30000.0f)

__global__ __launch_bounds__(256) void flash_attn(
    const bf16* __restrict__ q, const bf16* __restrict__ k,
    const bf16* __restrict__ vt, bf16* __restrict__ o, int S)
{
  __shared__ bf16 Ks[64 * 136];      // K tile row-major, stride 136
  __shared__ bf16 Vt[128 * 72];      // V^T tile: [d][kv], stride 72
  __shared__ bf16 Ps[4][32 * 72];    // per-wave P scratch, stride 72

  const int tid  = threadIdx.x;
  const int wave = tid >> 6;
  const int lane = tid & 63;
  const int quad = lane >> 4;
  const int l16  = lane & 15;

  const int bh = blockIdx.x;
  const int b  = bh >> 4, h = bh & 15;
  const int q0 = ((int)gridDim.y - 1 - (int)blockIdx.y) * 128;  // heavy first

  const bf16* Qb = q + ((long)b * S * 16 + h) * 128;
  const bf16* Kb = k + ((long)b * S * 16 + h) * 128;
  const bf16* Vg = vt + (long)bh * 128 * S;       // [d][s]
  bf16*       Ob = o + ((long)b * S * 16 + h) * 128;

  int kr[4], kc[4], vr[4], vc[4];
#pragma unroll
  for (int it = 0; it < 4; it++) {
    const int c = tid + it * 256;
    kr[it] = c >> 4;  kc[it] = (c & 15) * 8;   // K: 64 rows x 128 d
    vr[it] = c >> 3;  vc[it] = (c & 7) * 8;    // V^T: 128 d x 64 kv
  }

  short8 aq[2][4];
#pragma unroll
  for (int mi = 0; mi < 2; mi++)
#pragma unroll
    for (int kt = 0; kt < 4; kt++)
      aq[mi][kt] = *(const short8*)(
          Qb + (long)(q0 + wave * 32 + mi * 16 + l16) * 2048 + kt * 32 + quad * 8);

  float m_i[2][4], l_i[2][4];
  floatx4 oacc[2][8];
  const floatx4 zero4 = {0.f, 0.f, 0.f, 0.f};
#pragma unroll
  for (int mi = 0; mi < 2; mi++) {
#pragma unroll
    for (int r = 0; r < 4; r++) { m_i[mi][r] = NEG_BIG; l_i[mi][r] = 0.f; }
#pragma unroll
    for (int dt = 0; dt < 8; dt++) oacc[mi][dt] = zero4;
  }

  const int wrow0 = q0 + wave * 32;
  const int last  = q0 + 64;

  short8 kreg[4], vreg[4];
#pragma unroll
  for (int it = 0; it < 4; it++) {
    kreg[it] = *(const short8*)(Kb + (long)kr[it] * 2048 + kc[it]);
    vreg[it] = *(const short8*)(Vg + (long)vr[it] * S + vc[it]);
  }

  for (int kt0 = 0; kt0 <= last; kt0 += 64) {
    __syncthreads();

#pragma unroll
    for (int it = 0; it < 4; it++) {
      *(short8*)(Ks + kr[it] * 136 + kc[it]) = kreg[it];
      *(short8*)(Vt + vr[it] * 72 + vc[it]) = vreg[it];
    }
    __syncthreads();

    if (kt0 < last) {
      const int n0 = kt0 + 64;
#pragma unroll
      for (int it = 0; it < 4; it++) {
        kreg[it] = *(const short8*)(Kb + (long)(n0 + kr[it]) * 2048 + kc[it]);
        vreg[it] = *(const short8*)(Vg + (long)vr[it] * S + n0 + vc[it]);
      }
    }

    if (kt0 <= wrow0 + 31) {
      floatx4 sc[2][4];
#pragma unroll
      for (int mi = 0; mi < 2; mi++)
#pragma unroll
        for (int nt = 0; nt < 4; nt++) sc[mi][nt] = zero4;

      __builtin_amdgcn_s_setprio(1);
#pragma unroll
      for (int nt = 0; nt < 4; nt++)
#pragma unroll
        for (int kt = 0; kt < 4; kt++) {
          short8 bk = *(const short8*)(Ks + (nt * 16 + l16) * 136 + kt * 32 + quad * 8);
          sc[0][nt] = __builtin_amdgcn_mfma_f32_16x16x32_bf16(aq[0][kt], bk, sc[0][nt], 0, 0, 0);
          sc[1][nt] = __builtin_amdgcn_mfma_f32_16x16x32_bf16(aq[1][kt], bk, sc[1][nt], 0, 0, 0);
        }
      __builtin_amdgcn_s_setprio(0);

      // ---- pass 1: mask + row max (scores pre-scaled, log2 domain) ----
      const bool needmask = (kt0 + 63 > wrow0);
      float mx[2][4];
      int allskip = 1;
#pragma unroll
      for (int mi = 0; mi < 2; mi++) {
#pragma unroll
        for (int r = 0; r < 4; r++) {
          const int qr = wrow0 + mi * 16 + quad * 4 + r;
          float m = NEG_BIG;
          if (needmask) {
#pragma unroll
            for (int nt = 0; nt < 4; nt++) {
              const int kc2 = kt0 + nt * 16 + l16;
              float vsc = (kc2 <= qr) ? sc[mi][nt][r] : NEG_BIG;
              sc[mi][nt][r] = vsc;
              m = fmaxf(m, vsc);
            }
          } else {
#pragma unroll
            for (int nt = 0; nt < 4; nt++) m = fmaxf(m, sc[mi][nt][r]);
          }
          m = red16_max(m);
          mx[mi][r] = m;
          allskip &= (m <= m_i[mi][r] + 8.0f) ? 1 : 0;
        }
      }

      // ---- defer-max: rescale only when some row max grew past THR=8 ----
      if (!__all(allskip)) {
#pragma unroll
        for (int mi = 0; mi < 2; mi++) {
#pragma unroll
          for (int r = 0; r < 4; r++) {
            const float mnew = fmaxf(m_i[mi][r], mx[mi][r]);
            const float alpha = exp2f(m_i[mi][r] - mnew);
            m_i[mi][r] = mnew;
            l_i[mi][r] *= alpha;
#pragma unroll
            for (int dt = 0; dt < 8; dt++) oacc[mi][dt][r] *= alpha;
          }
        }
      }

      // ---- pass 2: exp + row sum against (possibly stale) m_i ----
#pragma unroll
      for (int mi = 0; mi < 2; mi++) {
#pragma unroll
        for (int r = 0; r < 4; r++) {
          float rs = 0.f;
#pragma unroll
          for (int nt = 0; nt < 4; nt++) {
            float p = exp2f(sc[mi][nt][r] - m_i[mi][r]);
            sc[mi][nt][r] = p;
            rs += p;
          }
          rs = red16_sum(rs);
          l_i[mi][r] += rs;
        }
      }

#pragma unroll
      for (int mi = 0; mi < 2; mi++)
#pragma unroll
        for (int nt = 0; nt < 4; nt++)
#pragma unroll
          for (int r = 0; r < 4; r++)
            Ps[wave][(mi * 16 + quad * 4 + r) * 72 + nt * 16 + l16] =
                __float2bfloat16(sc[mi][nt][r]);

      __builtin_amdgcn_s_setprio(1);
#pragma unroll
      for (int ks = 0; ks < 2; ks++) {
        short8 ap0 = *(const short8*)(&Ps[wave][(l16) * 72 + ks * 32 + quad * 8]);
        short8 ap1 = *(const short8*)(&Ps[wave][(16 + l16) * 72 + ks * 32 + quad * 8]);
#pragma unroll
        for (int dt = 0; dt < 8; dt++) {
          short8 bv = *(const short8*)(Vt + (dt * 16 + l16) * 72 + ks * 32 + quad * 8);
          oacc[0][dt] = __builtin_amdgcn_mfma_f32_16x16x32_bf16(ap0, bv, oacc[0][dt], 0, 0, 0);
          oacc[1][dt] = __builtin_amdgcn_mfma_f32_16x16x32_bf16(ap1, bv, oacc[1][dt], 0, 0, 0);
        }
      }
      __builtin_amdgcn_s_setprio(0);
    }
  }

#pragma unroll
  for (int mi = 0; mi < 2; mi++)
#pragma unroll
    for (int r = 0; r < 4; r++) {
      const float inv = 1.0f / l_i[mi][r];
      const long s = q0 + wave * 32 + mi * 16 + quad * 4 + r;
#pragma unroll
      for (int dt = 0; dt < 8; dt++)
        Ob[s * 2048 + dt * 16 + l16] = __float2bfloat16(oacc[mi][dt][r] * inv);
    }
}

// ---------------------------------------------------------------------------
extern "C" void kernel_launch(void* const* d_in, const int* in_sizes, int n_in,
                              void* d_out, int out_size, void* d_ws, size_t ws_size,
                              hipStream_t stream) {
  const float* x  = (const float*)d_in[0];
  const float* wq = (const float*)d_in[1];
  const float* wk = (const float*)d_in[2];
  const float* wv = (const float*)d_in[3];
  const float* wo = (const float*)d_in[4];
  float* out = (float*)d_out;

  const int B = 2, S = 2048, D = 2048, H = 16;
  const int M = B * S;                    // 4096
  const long tsz = (long)M * D;           // 8.39M elems
  const long wsz = (long)D * D;           // 4.19M elems

  if (ws_size < 4 * (size_t)tsz * sizeof(bf16)) return;   // 67 MB

  bf16* qb  = (bf16*)d_ws;
  bf16* kb  = qb + tsz;
  bf16* vtb = kb + tsz;                   // transposed V: [b][h][d][s]
  bf16* ab  = vtb + tsz;

  // d_out as scratch: xb (tsz) + wq' (wsz) + wk' (wsz) = exactly out bytes.
  bf16* xb  = (bf16*)d_out;
  bf16* wqb = xb + tsz;
  bf16* wkb = wqb + wsz;
  bf16* wvb = ab;                         // front half of ab (dead until flash)
  floatx2* rtab = (floatx2*)(ab + wsz);   // 1 MB rope table in ab's back half
  bf16* wob = qb;                         // qb dead after flash

  fused_pre<<<dim3((int)(wsz / 8 / 256), 6), 256, 0, stream>>>(
      x, wq, wk, wv, xb, wqb, wkb, wvb, rtab, wsz);

  qkv_gemm<<<dim3(16, 48), 256, 0, stream>>>(
      xb, wqb, wkb, wvb, qb, kb, vtb, rtab, M, D, D);

  flash_attn<<<dim3(B * H, S / 128), 256, 0, stream>>>(qb, kb, vtb, ab, S);

  cast_kernel<<<(int)(wsz / 8 / 256), 256, 0, stream>>>(wo, wob, wsz);
  gemm_out<<<dim3(32, 16), 256, 0, stream>>>(ab, wob, out, M, D, D);
}